// Round 6
// baseline (89.590 us; speedup 1.0000x reference)
//
#include <hip/hip_runtime.h>
#include <math.h>

#define PCEN_EPS 1e-6f

constexpr int Bn = 64, Cn = 80, Tn = 8000;
constexpr int ROWS = Bn * Cn;     // 5120
constexpr int TILE = 1024;        // elements per wave
constexpr int HALO = 512;         // warm-up samples; w^512 ~ 8e-10 for s=0.04
constexpr int EPL  = 16;          // tile elements per lane
constexpr int HEPL = 8;           // halo elements per lane
constexpr int TPR  = 8;           // tiles per row (8*1024 = 8192 >= 8000)

// pow for strictly-positive base on the HW transcendental pipe
__device__ __forceinline__ float fast_pow_pos(float b, float e) {
#if __has_builtin(__builtin_amdgcn_logf) && __has_builtin(__builtin_amdgcn_exp2f)
    return __builtin_amdgcn_exp2f(e * __builtin_amdgcn_logf(b));
#else
    return __exp2f(e * __log2f(b));
#endif
}

// R5 lesson: the two-phase + __syncthreads structure let the compiler sink the
// tile loads into phase B (VGPR=44 -> rematerialized loads stalling behind the
// barrier). This version has NO barrier and NO LDS: each wave owns one tile,
// reconstructing the IIR carry from a 512-sample halo (error ~1e-9 << 7e-2).
__global__ __launch_bounds__(256, 4)
void pcen_kernel(const float* __restrict__ x,
                 const float* __restrict__ logit_s,
                 const float* __restrict__ alpha,
                 const float* __restrict__ delta,
                 const float* __restrict__ log_r,
                 float* __restrict__ out)
{
    const int lane = threadIdx.x & 63;
    const int wid  = threadIdx.x >> 6;
    const int row  = blockIdx.x >> 1;                 // 2 blocks per row
    const int tile = ((blockIdx.x & 1) << 2) | wid;   // 4 adjacent tiles per block
    const int c    = row % Cn;

    // per-channel parameters (broadcast loads)
    const float s  = 1.0f / (1.0f + __expf(-logit_s[c]));
    const float w  = 1.0f - s;
    const float a  = fminf(fmaxf(alpha[c], 0.1f), 1.0f);
    const float dd = fmaxf(delta[c], 0.1f);
    const float rr = fminf(fmaxf(__expf(log_r[c]), 0.05f), 1.5f);
    const float d_r = fast_pow_pos(dd, rr);
    const float na  = -a;

    // w8p[i] = w^(8*2^i), i=0..6 (w8p[6] = w^512), by repeated squaring
    float w8p[7];
    {
        const float w2 = w * w, w4 = w2 * w2;
        w8p[0] = w4 * w4;
        #pragma unroll
        for (int i = 1; i < 7; ++i) w8p[i] = w8p[i - 1] * w8p[i - 1];
    }
    // w^(8*lane) and w^(16*lane)
    float w8L = 1.0f;
    #pragma unroll
    for (int b = 0; b < 6; ++b)
        if (lane & (1 << b)) w8L *= w8p[b];
    const float w16L = w8L * w8L;

    const float* __restrict__ xrow = x   + (size_t)row * Tn;
    float* __restrict__ orow       = out + (size_t)row * Tn;
    const int St = tile * TILE;
    const int tb = St + lane * EPL;
    const bool tvalid = (tb + EPL <= Tn);   // tile 7: lanes >= 52 are past the end

    // ---- tile loads (4 x dwordx4), zero-fill past end; relu in place ----
    float xv[EPL];
    if (tvalid) {
        #pragma unroll
        for (int q = 0; q < 4; ++q) {
            const float4 p = *reinterpret_cast<const float4*>(xrow + tb + 4 * q);
            xv[4 * q + 0] = p.x; xv[4 * q + 1] = p.y;
            xv[4 * q + 2] = p.z; xv[4 * q + 3] = p.w;
        }
    } else {
        #pragma unroll
        for (int j = 0; j < EPL; ++j) xv[j] = 0.0f;
    }
    #pragma unroll
    for (int j = 0; j < EPL; ++j) xv[j] = fmaxf(xv[j], 0.0f);

    // ---- carry-in P: exact x0 for tile 0, halo reduction otherwise ----
    float P;
    if (tile == 0) {
        P = __shfl(xv[0], 0, 64);   // m_0 = w*P + s*x0 = x0 exactly
    } else {
        const int hb = St - HALO + lane * HEPL;   // always in-bounds (St >= 1024)
        float hx[HEPL];
        #pragma unroll
        for (int q = 0; q < 2; ++q) {
            const float4 p = *reinterpret_cast<const float4*>(xrow + hb + 4 * q);
            hx[4 * q + 0] = p.x; hx[4 * q + 1] = p.y;
            hx[4 * q + 2] = p.z; hx[4 * q + 3] = p.w;
        }
        // Horner over this lane's 8 halo elems (carry 0)
        float yh = s * fmaxf(hx[0], 0.0f);
        #pragma unroll
        for (int j = 1; j < HEPL; ++j) yh = fmaf(yh, w, s * fmaxf(hx[j], 0.0f));
        // weight by w^(8*(63-lane)) then butterfly-sum: P = IIR state after halo
        float wrev = 1.0f;
        const int rl = lane ^ 63;
        #pragma unroll
        for (int b = 0; b < 6; ++b)
            if (rl & (1 << b)) wrev *= w8p[b];
        float z = yh * wrev;
        #pragma unroll
        for (int st = 0; st < 6; ++st) z += __shfl_xor(z, 1 << st, 64);
        P = z;
    }

    // ---- tile scan: per-lane Horner + Hillis-Steele (coef w^16 = w8p[st+1]) ----
    float y = s * xv[0];
    #pragma unroll
    for (int j = 1; j < EPL; ++j) y = fmaf(y, w, s * xv[j]);
    float Y = y;
    #pragma unroll
    for (int st = 0; st < 6; ++st) {
        const float Yup  = __shfl_up(Y, 1 << st, 64);
        const float cand = fmaf(w8p[st + 1], Yup, Y);
        Y = (lane >= (1 << st)) ? cand : Y;
    }
    const float Yprev = __shfl_up(Y, 1, 64);
    const float excl  = (lane == 0) ? 0.0f : Yprev;
    const float F     = fmaf(w16L, P, excl);   // m-state just before this lane's span

    // ---- pointwise pcen + store ----
    if (tvalid) {
        float mm = F;
        #pragma unroll
        for (int q = 0; q < 4; ++q) {
            float o[4];
            #pragma unroll
            for (int j = 0; j < 4; ++j) {
                const float xx = xv[4 * q + j];
                mm = fmaf(w, mm, s * xx);
                const float t = fast_pow_pos(PCEN_EPS + mm, na);
                o[j] = fast_pow_pos(fmaf(xx, t, dd), rr) - d_r;
            }
            *reinterpret_cast<float4*>(orow + tb + 4 * q) =
                make_float4(o[0], o[1], o[2], o[3]);
        }
    }
}

extern "C" void kernel_launch(void* const* d_in, const int* in_sizes, int n_in,
                              void* d_out, int out_size, void* d_ws, size_t ws_size,
                              hipStream_t stream) {
    const float* features = (const float*)d_in[0];
    const float* logit_s  = (const float*)d_in[1];
    const float* alpha    = (const float*)d_in[2];
    const float* delta    = (const float*)d_in[3];
    const float* log_r    = (const float*)d_in[4];
    float* out = (float*)d_out;

    // 2 blocks per row x 5120 rows; block = 4 adjacent tiles (halo reuse in L1/L2)
    pcen_kernel<<<ROWS * 2, 256, 0, stream>>>(features, logit_s, alpha, delta, log_r, out);
}

// Round 7
// 80.469 us; speedup vs baseline: 1.1133x; 1.1133x over previous
//
#include <hip/hip_runtime.h>
#include <math.h>

#define PCEN_EPS 1e-6f

constexpr int Bn = 64, Cn = 80, Tn = 8000;
constexpr int ROWS = Bn * Cn;     // 5120
constexpr int TILE = 1024;        // elements per wave
constexpr int HALO = 512;         // warm-up samples; w^512 ~ 8e-10 for s=0.04
constexpr int EPL  = 16;          // tile elements per lane
constexpr int HEPL = 8;           // halo elements per lane

// pow for strictly-positive base on the HW transcendental pipe
__device__ __forceinline__ float fast_pow_pos(float b, float e) {
#if __has_builtin(__builtin_amdgcn_logf) && __has_builtin(__builtin_amdgcn_exp2f)
    return __builtin_amdgcn_exp2f(e * __builtin_amdgcn_logf(b));
#else
    return __exp2f(e * __log2f(b));
#endif
}

// R4-R6 lesson: whenever the allocator drops the x-tile from registers
// (VGPR=24/44), it re-loads x from global in the pointwise pass -> serial
// load-wait chains -> 80-150us. The asm "+v" pins below make xv opaque after
// the load, forcing single-load register residency (~55 VGPR, no spill room
// issues under the 128 cap).
__global__ __launch_bounds__(256, 4)
void pcen_kernel(const float* __restrict__ x,
                 const float* __restrict__ logit_s,
                 const float* __restrict__ alpha,
                 const float* __restrict__ delta,
                 const float* __restrict__ log_r,
                 float* __restrict__ out)
{
    const int lane = threadIdx.x & 63;
    const int wid  = threadIdx.x >> 6;
    const int row  = blockIdx.x >> 1;                 // 2 blocks per row
    const int tile = ((blockIdx.x & 1) << 2) | wid;   // 4 adjacent tiles per block
    const int c    = row % Cn;

    const float* __restrict__ xrow = x   + (size_t)row * Tn;
    float* __restrict__ orow       = out + (size_t)row * Tn;
    const int St = tile * TILE;
    const int tb = St + lane * EPL;
    const bool tvalid = (tb + EPL <= Tn);   // tile 7: lanes >= 52 past the end

    // ---- issue ALL global loads first (tile + halo together, latencies overlap) ----
    float xv[EPL];
    if (tvalid) {
        #pragma unroll
        for (int q = 0; q < 4; ++q) {
            const float4 p = *reinterpret_cast<const float4*>(xrow + tb + 4 * q);
            xv[4 * q + 0] = p.x; xv[4 * q + 1] = p.y;
            xv[4 * q + 2] = p.z; xv[4 * q + 3] = p.w;
        }
    } else {
        #pragma unroll
        for (int j = 0; j < EPL; ++j) xv[j] = 0.0f;
    }
    float hx[HEPL];
    const bool haloed = (tile != 0);
    if (haloed) {
        const int hb = St - HALO + lane * HEPL;   // in-bounds (St >= 1024)
        #pragma unroll
        for (int q = 0; q < 2; ++q) {
            const float4 p = *reinterpret_cast<const float4*>(xrow + hb + 4 * q);
            hx[4 * q + 0] = p.x; hx[4 * q + 1] = p.y;
            hx[4 * q + 2] = p.z; hx[4 * q + 3] = p.w;
        }
    }

    // per-channel parameters (broadcast loads; scheduled under the vmem waits)
    const float s  = 1.0f / (1.0f + __expf(-logit_s[c]));
    const float w  = 1.0f - s;
    const float a  = fminf(fmaxf(alpha[c], 0.1f), 1.0f);
    const float dd = fmaxf(delta[c], 0.1f);
    const float rr = fminf(fmaxf(__expf(log_r[c]), 0.05f), 1.5f);
    const float d_r = fast_pow_pos(dd, rr);
    const float na  = -a;

    // w8p[i] = w^(8*2^i), i=0..6, by repeated squaring
    float w8p[7];
    {
        const float w2 = w * w, w4 = w2 * w2;
        w8p[0] = w4 * w4;
        #pragma unroll
        for (int i = 1; i < 7; ++i) w8p[i] = w8p[i - 1] * w8p[i - 1];
    }
    float w8L = 1.0f;
    #pragma unroll
    for (int b = 0; b < 6; ++b)
        if (lane & (1 << b)) w8L *= w8p[b];
    const float w16L = w8L * w8L;

    // relu, then PIN: xv must stay in VGPRs from here to the store
    #pragma unroll
    for (int j = 0; j < EPL; ++j) xv[j] = fmaxf(xv[j], 0.0f);
    #pragma unroll
    for (int j = 0; j < EPL; ++j) asm volatile("" : "+v"(xv[j]));

    // ---- carry-in P: exact x0 for tile 0, halo reduction otherwise ----
    float P;
    if (!haloed) {
        P = __shfl(xv[0], 0, 64);   // m_0 = w*P + s*x0 = x0 exactly
    } else {
        // Horner over this lane's 8 halo elems (carry 0)
        float yh = s * fmaxf(hx[0], 0.0f);
        #pragma unroll
        for (int j = 1; j < HEPL; ++j) yh = fmaf(yh, w, s * fmaxf(hx[j], 0.0f));
        // weight by w^(8*(63-lane)), butterfly-sum -> IIR state after halo
        float wrev = 1.0f;
        const int rl = lane ^ 63;
        #pragma unroll
        for (int b = 0; b < 6; ++b)
            if (rl & (1 << b)) wrev *= w8p[b];
        float z = yh * wrev;
        #pragma unroll
        for (int st = 0; st < 6; ++st) z += __shfl_xor(z, 1 << st, 64);
        P = z;
    }

    // ---- tile scan: per-lane Horner + Hillis-Steele (coef w^16 = w8p[st+1]) ----
    float y = s * xv[0];
    #pragma unroll
    for (int j = 1; j < EPL; ++j) y = fmaf(y, w, s * xv[j]);
    float Y = y;
    #pragma unroll
    for (int st = 0; st < 6; ++st) {
        const float Yup  = __shfl_up(Y, 1 << st, 64);
        const float cand = fmaf(w8p[st + 1], Yup, Y);
        Y = (lane >= (1 << st)) ? cand : Y;
    }
    const float Yprev = __shfl_up(Y, 1, 64);
    const float excl  = (lane == 0) ? 0.0f : Yprev;
    const float F     = fmaf(w16L, P, excl);   // m-state just before this lane's span

    // ---- pointwise pcen + store (xv read straight from pinned regs) ----
    if (tvalid) {
        float mm = F;
        #pragma unroll
        for (int q = 0; q < 4; ++q) {
            float o[4];
            #pragma unroll
            for (int j = 0; j < 4; ++j) {
                const float xx = xv[4 * q + j];
                mm = fmaf(w, mm, s * xx);
                const float t = fast_pow_pos(PCEN_EPS + mm, na);
                o[j] = fast_pow_pos(fmaf(xx, t, dd), rr) - d_r;
            }
            *reinterpret_cast<float4*>(orow + tb + 4 * q) =
                make_float4(o[0], o[1], o[2], o[3]);
        }
    }
}

extern "C" void kernel_launch(void* const* d_in, const int* in_sizes, int n_in,
                              void* d_out, int out_size, void* d_ws, size_t ws_size,
                              hipStream_t stream) {
    const float* features = (const float*)d_in[0];
    const float* logit_s  = (const float*)d_in[1];
    const float* alpha    = (const float*)d_in[2];
    const float* delta    = (const float*)d_in[3];
    const float* log_r    = (const float*)d_in[4];
    float* out = (float*)d_out;

    // 2 blocks per row x 5120 rows; block = 4 adjacent tiles (halo reuse in L1/L2)
    pcen_kernel<<<ROWS * 2, 256, 0, stream>>>(features, logit_s, alpha, delta, log_r, out);
}

// Round 8
// 68.858 us; speedup vs baseline: 1.3011x; 1.1686x over previous
//
#include <hip/hip_runtime.h>
#include <math.h>

#define PCEN_EPS 1e-6f

constexpr int Bn = 64, Cn = 80, Tn = 8000;
constexpr int ROWS = Bn * Cn;     // 5120
constexpr int TILE = 1024;        // elements per wave
constexpr int HALO = 512;         // warm-up samples; w^512 ~ 8e-10 for s=0.04
constexpr int CH   = 256;         // sub-chunk = one contiguous 1KB load

// pow for strictly-positive base on the HW transcendental pipe
__device__ __forceinline__ float fast_pow_pos(float b, float e) {
#if __has_builtin(__builtin_amdgcn_logf) && __has_builtin(__builtin_amdgcn_exp2f)
    return __builtin_amdgcn_exp2f(e * __builtin_amdgcn_logf(b));
#else
    return __exp2f(e * __log2f(b));
#endif
}

// R7 lesson: EPL=16 made lanes 64B apart per dwordx4 -> 64 cache lines per
// load/store inst (4x the L1/TA transactions of a contiguous pattern). That
// transaction rate, not HBM bytes, was the ~2.6TB/s plateau. This version uses
// lane-CONTIGUOUS 1KB loads/stores (4 lanes per 64B line): lane owns elements
// 256q + 4*lane .. +3 of its tile; scan = 4 independent 6-shfl chunk scans
// (coef w^4) + 3-fma carry chain across chunks.
__global__ __launch_bounds__(256, 4)
void pcen_kernel(const float* __restrict__ x,
                 const float* __restrict__ logit_s,
                 const float* __restrict__ alpha,
                 const float* __restrict__ delta,
                 const float* __restrict__ log_r,
                 float* __restrict__ out)
{
    const int lane = threadIdx.x & 63;
    const int wid  = threadIdx.x >> 6;
    const int row  = blockIdx.x >> 1;                 // 2 blocks per row
    const int tile = ((blockIdx.x & 1) << 2) | wid;   // 4 adjacent tiles per block
    const int c    = row % Cn;

    const float* __restrict__ xrow = x   + (size_t)row * Tn;
    float* __restrict__ orow       = out + (size_t)row * Tn;
    const int St = tile * TILE;
    const int l4 = lane * 4;

    // ---- issue ALL global loads first (contiguous 1KB each; latencies overlap) ----
    float xv[4][4];
    #pragma unroll
    for (int q = 0; q < 4; ++q) {
        const int tb = St + CH * q + l4;
        if (tb + 4 <= Tn) {
            const float4 p = *reinterpret_cast<const float4*>(xrow + tb);
            xv[q][0] = p.x; xv[q][1] = p.y; xv[q][2] = p.z; xv[q][3] = p.w;
        } else {
            xv[q][0] = xv[q][1] = xv[q][2] = xv[q][3] = 0.0f;
        }
    }
    float hx[2][4];
    const bool haloed = (tile != 0);
    if (haloed) {
        #pragma unroll
        for (int h = 0; h < 2; ++h) {
            const int hb = St - HALO + CH * h + l4;   // in-bounds (St >= 1024)
            const float4 p = *reinterpret_cast<const float4*>(xrow + hb);
            hx[h][0] = p.x; hx[h][1] = p.y; hx[h][2] = p.z; hx[h][3] = p.w;
        }
    }

    // per-channel parameters (uniform; scheduled under the vmem waits)
    const float s  = 1.0f / (1.0f + __expf(-logit_s[c]));
    const float w  = 1.0f - s;
    const float a  = fminf(fmaxf(alpha[c], 0.1f), 1.0f);
    const float dd = fmaxf(delta[c], 0.1f);
    const float rr = fminf(fmaxf(__expf(log_r[c]), 0.05f), 1.5f);
    const float d_r = fast_pow_pos(dd, rr);
    const float na  = -a;

    // w4p[i] = w^(4*2^i), i=0..6 (w4p[6] = w^256), by repeated squaring
    float w4p[7];
    {
        const float w2 = w * w;
        w4p[0] = w2 * w2;
        #pragma unroll
        for (int i = 1; i < 7; ++i) w4p[i] = w4p[i - 1] * w4p[i - 1];
    }
    const float w256 = w4p[6];
    float w4L = 1.0f;           // w^(4*lane)
    #pragma unroll
    for (int b = 0; b < 6; ++b)
        if (lane & (1 << b)) w4L *= w4p[b];

    // relu, then PIN xv into VGPRs (no re-load in the pointwise pass)
    #pragma unroll
    for (int q = 0; q < 4; ++q)
        #pragma unroll
        for (int j = 0; j < 4; ++j) xv[q][j] = fmaxf(xv[q][j], 0.0f);
    #pragma unroll
    for (int q = 0; q < 4; ++q)
        #pragma unroll
        for (int j = 0; j < 4; ++j) asm volatile("" : "+v"(xv[q][j]));

    // ---- carry-in P (state just before tile start) ----
    float P;
    if (!haloed) {
        P = __shfl(xv[0][0], 0, 64);   // m_0 = w*P + s*x0 = x0 exactly
    } else {
        // per-lane Horner over each halo sub-chunk (carry 0)
        float yh0 = s * fmaxf(hx[0][0], 0.0f);
        float yh1 = s * fmaxf(hx[1][0], 0.0f);
        #pragma unroll
        for (int j = 1; j < 4; ++j) {
            yh0 = fmaf(yh0, w, s * fmaxf(hx[0][j], 0.0f));
            yh1 = fmaf(yh1, w, s * fmaxf(hx[1][j], 0.0f));
        }
        // weight by w^(4*(63-lane)), butterfly-sum: P = w^256*S0 + S1
        float wrev = 1.0f;
        const int rl = lane ^ 63;
        #pragma unroll
        for (int b = 0; b < 6; ++b)
            if (rl & (1 << b)) wrev *= w4p[b];
        float z = wrev * fmaf(w256, yh0, yh1);
        #pragma unroll
        for (int st = 0; st < 6; ++st) z += __shfl_xor(z, 1 << st, 64);
        P = z;
    }

    // ---- 4 independent chunk scans (coef w^4), then chunk-carry chain ----
    float Y[4];
    #pragma unroll
    for (int q = 0; q < 4; ++q) {
        float y = s * xv[q][0];
        #pragma unroll
        for (int j = 1; j < 4; ++j) y = fmaf(y, w, s * xv[q][j]);
        Y[q] = y;
    }
    #pragma unroll
    for (int st = 0; st < 6; ++st) {
        float Yup[4];
        #pragma unroll
        for (int q = 0; q < 4; ++q) Yup[q] = __shfl_up(Y[q], 1 << st, 64);
        #pragma unroll
        for (int q = 0; q < 4; ++q) {
            const float cand = fmaf(w4p[st], Yup[q], Y[q]);
            Y[q] = (lane >= (1 << st)) ? cand : Y[q];
        }
    }
    float Yx[4], T[4];
    #pragma unroll
    for (int q = 0; q < 4; ++q) {
        const float Yp = __shfl_up(Y[q], 1, 64);
        Yx[q] = (lane == 0) ? 0.0f : Yp;          // exclusive scan
        T[q]  = __shfl(Y[q], 63, 64);             // chunk total
    }
    // state before chunk q: G0 = P; G_{q+1} = w^256*G_q + T_q
    float G[4];
    G[0] = P;
    G[1] = fmaf(w256, G[0], T[0]);
    G[2] = fmaf(w256, G[1], T[1]);
    G[3] = fmaf(w256, G[2], T[2]);

    // ---- pointwise pcen + contiguous stores ----
    #pragma unroll
    for (int q = 0; q < 4; ++q) {
        const int tb = St + CH * q + l4;
        if (tb + 4 <= Tn) {
            float mm = fmaf(w4L, G[q], Yx[q]);    // state before this lane's 4 elems
            float o[4];
            #pragma unroll
            for (int j = 0; j < 4; ++j) {
                const float xx = xv[q][j];
                mm = fmaf(w, mm, s * xx);
                const float t = fast_pow_pos(PCEN_EPS + mm, na);
                o[j] = fast_pow_pos(fmaf(xx, t, dd), rr) - d_r;
            }
            *reinterpret_cast<float4*>(orow + tb) = make_float4(o[0], o[1], o[2], o[3]);
        }
    }
}

extern "C" void kernel_launch(void* const* d_in, const int* in_sizes, int n_in,
                              void* d_out, int out_size, void* d_ws, size_t ws_size,
                              hipStream_t stream) {
    const float* features = (const float*)d_in[0];
    const float* logit_s  = (const float*)d_in[1];
    const float* alpha    = (const float*)d_in[2];
    const float* delta    = (const float*)d_in[3];
    const float* log_r    = (const float*)d_in[4];
    float* out = (float*)d_out;

    // 2 blocks per row x 5120 rows; block = 4 adjacent tiles (halo reuse in L1/L2)
    pcen_kernel<<<ROWS * 2, 256, 0, stream>>>(features, logit_s, alpha, delta, log_r, out);
}